// Round 17
// baseline (227.921 us; speedup 1.0000x reference)
//
#include <hip/hip_runtime.h>
#include <math.h>

typedef unsigned short u16;
typedef unsigned int u32;
typedef __attribute__((ext_vector_type(8))) _Float16 half8;   // fp16x8
typedef __attribute__((ext_vector_type(2))) _Float16 half2v;  // fp16x2
typedef __attribute__((ext_vector_type(8))) u16 ushort8;
typedef __attribute__((ext_vector_type(4))) float f32x4;
typedef __attribute__((ext_vector_type(4))) int int4v;

__device__ __forceinline__ u16 f2h(float f) {
    union { u16 u; _Float16 h; } c; c.h = (_Float16)f; return c.u;
}

#if __has_builtin(__builtin_amdgcn_fdot2)
#define FDOT2(a, b, c) __builtin_amdgcn_fdot2((a), (b), (c), false)
#else
#define FDOT2(a, b, c) fmaf((float)(a)[0], (float)(b)[0], \
                        fmaf((float)(a)[1], (float)(b)[1], (c)))
#endif

// async global(16B) -> LDS, per-lane source addr, wave-linear LDS dest
__device__ __forceinline__ void gload16(void* lds, const void* g) {
    __builtin_amdgcn_global_load_lds(
        (const __attribute__((address_space(1))) u32*)g,
        (__attribute__((address_space(3))) u32*)lds,
        16, 0, 0);
}

// ---------------------------------------------------------------------------
// GEMM body: C[M,512] = A[M,512](fp16) @ Bt[512,512](fp16,[n][k]) + bias.
// r12-proven structure (60 us, FETCH 19 MB): 2-phase double-buffer, 32 KB
// LDS, one __syncthreads per k-step, STAGE(next) before COMPUTE(current).
// [Counted-vmcnt deep pipelines rejected: r10/r11/r14 all regressed.]
// LDS tile [128][32]u16, XOR slot-swizzle (verified r6: bank conflicts -> 0).
// OUTMODE: 0 = f32 store, 1 = fp16 store, 2 = f32 nontemporal store.
// ---------------------------------------------------------------------------
template <int OUTMODE>
__device__ __forceinline__ void gemm_body(
    const u16* A, const u16* Bt, const float* bias, void* Cout, int Mout,
    int m0, int n0, u16* As0, u16* As1, u16* Bs0, u16* Bs1)
{
    const int tid  = threadIdx.x;
    const int wave = tid >> 6;
    const int lane = tid & 63;
    const int wr = (wave >> 1) * 64;
    const int wc = (wave & 1) * 64;

    f32x4 acc[4][4];
#pragma unroll
    for (int i = 0; i < 4; ++i)
#pragma unroll
        for (int j = 0; j < 4; ++j) acc[i][j] = (f32x4){0.f, 0.f, 0.f, 0.f};

    const int srow  = lane >> 2;                              // 0..15
    const int scolG = ((lane & 3) ^ ((srow >> 1) & 3)) * 8;   // swizzled global col
    const size_t gOffA = (size_t)(m0 + wave * 32 + srow) * 512 + scolG;
    const size_t gOffB = (size_t)(n0 + wave * 32 + srow) * 512 + scolG;
    const int lOff = wave * 1024 + srow * 32 + (lane & 3) * 8;  // linear dest

    const int fR = ((lane & 15) >> 1) & 3;
    const int paOff = (wr + (lane & 15)) * 32 + ((lane >> 4) ^ fR) * 8;
    const int pbOff = (wc + (lane & 15)) * 32 + ((lane >> 4) ^ fR) * 8;

    auto STAGE = [&](u16* sa, u16* sb, int ko) {
        gload16(sa + lOff,       A  + gOffA + ko);
        gload16(sa + lOff + 512, A  + gOffA + ko + 16 * 512);
        gload16(sb + lOff,       Bt + gOffB + ko);
        gload16(sb + lOff + 512, Bt + gOffB + ko + 16 * 512);
    };
    auto COMPUTE = [&](const u16* sa, const u16* sb) {
        half8 af[4], bf[4];
#pragma unroll
        for (int i = 0; i < 4; ++i) af[i] = *(const half8*)(sa + paOff + i * 512);
#pragma unroll
        for (int j = 0; j < 4; ++j) bf[j] = *(const half8*)(sb + pbOff + j * 512);
#pragma unroll
        for (int i = 0; i < 4; ++i)
#pragma unroll
            for (int j = 0; j < 4; ++j)
                acc[i][j] = __builtin_amdgcn_mfma_f32_16x16x32_f16(
                    af[i], bf[j], acc[i][j], 0, 0, 0);
    };

    STAGE(As0, Bs0, 0);
    __syncthreads();
#pragma unroll
    for (int kt = 0; kt < 16; kt += 2) {
        STAGE(As1, Bs1, (kt + 1) * 32);
        COMPUTE(As0, Bs0);
        __syncthreads();
        if (kt + 2 < 16) STAGE(As0, Bs0, (kt + 2) * 32);
        COMPUTE(As1, Bs1);
        __syncthreads();
    }

    const int ccol  = n0 + wc + (lane & 15);
    const int crow0 = m0 + wr + (lane >> 4) * 4;
#pragma unroll
    for (int j = 0; j < 4; ++j) {
        const float b = bias[ccol + j * 16];
#pragma unroll
        for (int i = 0; i < 4; ++i) {
#pragma unroll
            for (int r = 0; r < 4; ++r) {
                int row = crow0 + i * 16 + r;
                if (row < Mout) {
                    float v = acc[i][j][r] + b;
                    size_t off = (size_t)row * 512 + ccol + j * 16;
                    if (OUTMODE == 0)      ((float*)Cout)[off] = v;
                    else if (OUTMODE == 1) ((u16*)Cout)[off] = f2h(v);
                    else __builtin_nontemporal_store(v, (float*)Cout + off);
                }
            }
        }
    }
}

// Q and K projections in ONE dispatch, XCD-grouped block mapping (r12,
// verified FETCH 70->19 MB). The CSR scatter blocks come FIRST (bids
// 0..nScat8-1, nScat8 a multiple of 8 so the GEMM's bid%8 XCD invariant
// holds): scatter has no dependency on the GEMM and is latency-bound
// atomics with no LDS/MFMA footprint -> it retires during the GEMM's
// ramp-up instead of as a serial ~11 us tail (r15/r16 counters).
// GEMM blocks: gbid = bid - nScat8; the 8 blocks sharing an A M-tile get
// gbid = 64*(m/8) + 8*s + (m%8) => same XCD, adjacent dispatch order.
__global__ __launch_bounds__(256) void gemm_qk(
    const u16* __restrict__ hh, const u16* __restrict__ Wqt,
    const u16* __restrict__ Wkt, const float* __restrict__ bqp,
    const float* __restrict__ bkp, u16* __restrict__ Qh,
    u16* __restrict__ Kb, int nPad,
    const int* __restrict__ rows, const int* __restrict__ cols,
    int* __restrict__ cursor, int* __restrict__ colc, int E, int nScat8)
{
    __shared__ __align__(16) u16 As0[4096], As1[4096], Bs0[4096], Bs1[4096];
    const int bid = blockIdx.x;
    if (bid < nScat8) {
        // ---- fused CSR scatter (runs concurrently with the GEMM) ----
        int i = bid * 256 + threadIdx.x;
        if (i < E) {
            int pos = atomicAdd(&cursor[rows[i]], 1);
            colc[pos] = cols[i];
        }
        return;
    }
    const int gbid = bid - nScat8;
    const int m = (gbid >> 6) * 8 + (gbid & 7);
    const int s = (gbid >> 3) & 7;
    if (m >= nPad / 128) return;
    const int z = s >> 2;        // 0: Q, 1: K
    const int n = s & 3;         // N-tile

    const u16* Bt = z ? Wkt : Wqt;
    const float* bias = z ? bkp : bqp;
    u16* out = z ? Kb : Qh;
    gemm_body<1>(hh, Bt, bias, out, nPad, m * 128, n * 128,
                 As0, As1, Bs0, Bs1);
}

// Wo projection, XCD-grouping with 4 sharers per A M-tile:
// bid = 32*(m/8) + 8*s + (m%8), s in 0..3. NT store (output never re-read).
__global__ __launch_bounds__(256) void gemm_wo(
    const u16* __restrict__ A, const u16* __restrict__ Wot,
    const float* __restrict__ bo, float* __restrict__ C, int Mout, int nPad)
{
    const int bid = blockIdx.x;
    const int m = (bid >> 5) * 8 + (bid & 7);
    const int s = (bid >> 3) & 3;
    if (m >= nPad / 128) return;

    __shared__ __align__(16) u16 As0[4096], As1[4096], Bs0[4096], Bs1[4096];
    gemm_body<2>(A, Wot, bo, C, Mout, m * 128, s * 128,
                 As0, As1, Bs0, Bs1);
}

// ---------------------------------------------------------------------------
// prep: fused conv_h (h f32 -> fp16, pad zeroed) + hist (4 edges/thread) +
// conv_w. Grid: [0,nbH) conv_h, [nbH,nbH+nbE4) hist, [nbH+nbE4,+192) conv_w.
// ---------------------------------------------------------------------------
__global__ __launch_bounds__(256) void prep(
    const float* __restrict__ h, u16* __restrict__ hh, int nN,
    const int* __restrict__ rows, int* __restrict__ deg, int E,
    const float* __restrict__ Wq, const float* __restrict__ Wk,
    const float* __restrict__ Wo, const float* __restrict__ bq,
    const float* __restrict__ bk,
    u16* __restrict__ Wqt, u16* __restrict__ Wkt, u16* __restrict__ Wot,
    float* __restrict__ bqp, float* __restrict__ bkp,
    int nbH, int nbE4)
{
    __shared__ float T[64][65];
    const int tid = threadIdx.x;
    const int b = blockIdx.x;

    if (b < nbH) {
        // ---- conv_h ----
        int t = b * 256 + tid;
        size_t e = (size_t)t * 8;
        int row = (int)(e >> 9);
        ushort8 o;
        if (row < nN) {
            f32x4 a = *(const f32x4*)(h + e);
            f32x4 bb = *(const f32x4*)(h + e + 4);
            float x[8] = {a.x, a.y, a.z, a.w, bb.x, bb.y, bb.z, bb.w};
#pragma unroll
            for (int i = 0; i < 8; ++i) o[i] = f2h(x[i]);
        } else {
            o = (ushort8){0,0,0,0,0,0,0,0};
        }
        *(ushort8*)(hh + e) = o;
        return;
    }
    if (b < nbH + nbE4) {
        // ---- hist: 4 edges per thread ----
        int i = ((b - nbH) * 256 + tid) * 4;
        if (i + 3 < E) {
            int4v r = *(const int4v*)(rows + i);
            atomicAdd(&deg[r.x], 1);
            atomicAdd(&deg[r.y], 1);
            atomicAdd(&deg[r.z], 1);
            atomicAdd(&deg[r.w], 1);
        } else {
            for (int t = i; t < E; ++t) atomicAdd(&deg[rows[t]], 1);
        }
        return;
    }
    // ---- conv_w ----  (192 blocks: z = rem>>6, by = (rem&63)>>3, bx = rem&7)
    int rem = b - nbH - nbE4;
    const int z = rem >> 6;
    const int X = (rem & 7) * 64;
    const int Y = ((rem >> 3) & 7) * 64;

    const int r4 = tid >> 4;
    const int c4 = (tid & 15) * 4;
    if (z < 2) {
        const float* W = z ? Wk : Wq;
#pragma unroll
        for (int rr = 0; rr < 64; rr += 16) {
            f32x4 v = *(const f32x4*)(W + (size_t)(X + rr + r4) * 512 + Y + c4);
            T[rr + r4][c4 + 0] = v.x; T[rr + r4][c4 + 1] = v.y;
            T[rr + r4][c4 + 2] = v.z; T[rr + r4][c4 + 3] = v.w;
        }
    } else {
#pragma unroll
        for (int rr = 0; rr < 64; rr += 16) {
            int p2 = (rr + r4) * 8 + (X >> 6);   // perm(X + rr + r4)
            f32x4 v = *(const f32x4*)(Wo + (size_t)p2 * 512 + Y + c4);
            T[rr + r4][c4 + 0] = v.x; T[rr + r4][c4 + 1] = v.y;
            T[rr + r4][c4 + 2] = v.z; T[rr + r4][c4 + 3] = v.w;
        }
    }
    __syncthreads();

    const int cc = tid >> 2;
    const int ks = (tid & 3) * 16;
    const int pc = Y + cc;
    const int ro = (z < 2) ? ((pc & 7) * 64 + (pc >> 3)) : pc;
    ushort8 h0, h1;
#pragma unroll
    for (int t = 0; t < 8; ++t) {
        h0[t] = f2h(T[ks + t][cc]);
        h1[t] = f2h(T[ks + 8 + t][cc]);
    }
    size_t o = (size_t)ro * 512 + X + ks;
    if (z == 0) {
        *(ushort8*)(Wqt + o) = h0; *(ushort8*)(Wqt + o + 8) = h1;
    } else if (z == 1) {
        *(ushort8*)(Wkt + o) = h0; *(ushort8*)(Wkt + o + 8) = h1;
    } else {
        *(ushort8*)(Wot + o) = h0; *(ushort8*)(Wot + o + 8) = h1;
        if (rem == 128) {   // z==2, bx==0, by==0
            for (int bi = tid; bi < 512; bi += 256) {
                int pp = (bi & 63) * 8 + (bi >> 6);
                bqp[bi] = bq[pp];
                bkp[bi] = bk[pp];
            }
        }
    }
}

// ---------------------------------------------------------------------------
// Single-dispatch CSR scan: block b redundantly sums deg over chunks < b
// (max ~100 KB of reads at nb=13 -- trivial), then scans its own chunk.
// ---------------------------------------------------------------------------
#define SCAN_CHUNK 2048

__global__ __launch_bounds__(256) void scan_all(
    const int* __restrict__ deg, int* __restrict__ rowptr,
    int* __restrict__ cursor, int n, int nb)
{
    const int t = threadIdx.x;
    const int b = blockIdx.x;
    const int lane = t & 63, wv = t >> 6;
    __shared__ int ws[4], wsum[4];

    // prefix over preceding chunks
    int pre = 0;
    for (int i = t; i < b * SCAN_CHUNK; i += 256) pre += deg[i];
#pragma unroll
    for (int off = 1; off < 64; off <<= 1) pre += __shfl_xor(pre, off, 64);
    if (lane == 0) ws[wv] = pre;
    __syncthreads();
    const int boff = ws[0] + ws[1] + ws[2] + ws[3];

    // scan own chunk (8 elems/thread)
    int base = b * SCAN_CHUNK + t * 8;
    int v[8];
    int s = 0;
#pragma unroll
    for (int i = 0; i < 8; ++i) {
        int g = base + i;
        v[i] = (g < n) ? deg[g] : 0;
        s += v[i];
    }
    int inc = s;
#pragma unroll
    for (int off = 1; off < 64; off <<= 1) {
        int x = __shfl_up(inc, off, 64);
        if (lane >= off) inc += x;
    }
    if (lane == 63) wsum[wv] = inc;
    __syncthreads();
    int excl = boff + inc - s;
    for (int i = 0; i < wv; ++i) excl += wsum[i];
#pragma unroll
    for (int i = 0; i < 8; ++i) {
        int g = base + i;
        if (g < n) { rowptr[g] = excl; cursor[g] = excl; }
        excl += v[i];
    }
    if (b == nb - 1 && t == 0)
        rowptr[n] = boff + wsum[0] + wsum[1] + wsum[2] + wsum[3];
}

// ---------------------------------------------------------------------------
// Fused SDDMM + online segment softmax + SpMM. Head-major layout:
// lane l -> head l>>3, dims (l&7)*8..+7. One wave per node, 4 nodes/block.
// 8-edge unroll + depth-8 prefetch (8 KB in flight/wave). Packed fp16 math.
// setprio(1) around compute (T5, independent barrier-free waves). agg store
// CACHED (read 4x by gemm_wo's same-XCD sharers).
// v == k (source bug): K row loaded for the dot is reused for aggregation.
// ---------------------------------------------------------------------------
__global__ __launch_bounds__(256) void node_agg(
    const u16* __restrict__ Qh, const u16* __restrict__ Kb,
    const int* __restrict__ rowptr, const int* __restrict__ colc,
    u16* __restrict__ aggb, int nN)
{
    int node = blockIdx.x * 4 + (threadIdx.x >> 6);
    int lane = threadIdx.x & 63;
    if (node >= nN) return;
    size_t base = (size_t)node * 512 + lane * 8;

    half8 qv = __builtin_nontemporal_load((const half8*)(Qh + base));
    half2v q2[4];
#pragma unroll
    for (int i = 0; i < 4; ++i) q2[i] = (half2v){qv[2 * i], qv[2 * i + 1]};

    int start = rowptr[node];
    int deg   = rowptr[node + 1] - start;
    const int* cp = colc + start;
    const size_t loff = (size_t)lane * 8;

    float m = -__builtin_inff();
    float den = 0.f;
    half2v acc2[4];
#pragma unroll
    for (int i = 0; i < 4; ++i) acc2[i] = (half2v){(_Float16)0.f, (_Float16)0.f};

    if (deg > 0) {
        const int dl = deg - 1;
        half8 k[8];
#pragma unroll
        for (int t = 0; t < 8; ++t) {
            int it = t < dl ? t : dl;
            k[t] = *(const half8*)(Kb + (size_t)cp[it] * 512 + loff);
        }
        for (int j = 0; j < deg; j += 8) {
            half8 nx[8];
#pragma unroll
            for (int t = 0; t < 8; ++t) {
                int it = j + 8 + t < dl ? j + 8 + t : dl;
                nx[t] = *(const half8*)(Kb + (size_t)cp[it] * 512 + loff);
            }

            __builtin_amdgcn_s_setprio(1);
            float p[8];
#pragma unroll
            for (int t = 0; t < 8; ++t) {
                float s = 0.f;
#pragma unroll
                for (int i = 0; i < 4; ++i) {
                    half2v bb = (half2v){k[t][2 * i], k[t][2 * i + 1]};
                    s = FDOT2(q2[i], bb, s);
                }
                p[t] = s;
            }
#pragma unroll
            for (int off = 1; off < 8; off <<= 1) {
#pragma unroll
                for (int t = 0; t < 8; ++t) p[t] += __shfl_xor(p[t], off, 64);
            }

            // defer-max (THR=4, fp16-acc-safe): one check per 8-edge group
            float pm = p[0];
#pragma unroll
            for (int t = 1; t < 8; ++t) pm = fmaxf(pm, p[t]);
            if (__any(pm > m + 4.f)) {
                float mn = fmaxf(m, pm);
                float sc = __expf(m - mn);   // first group: exp(-inf)=0
                den *= sc;
                _Float16 sch = (_Float16)sc;
                half2v sc2 = {sch, sch};
#pragma unroll
                for (int i = 0; i < 4; ++i) acc2[i] *= sc2;
                m = mn;
            }
#pragma unroll
            for (int t = 0; t < 8; ++t) {
                float w = (j + t < deg) ? __expf(p[t] - m) : 0.f;  // <= e^4
                den += w;
                _Float16 wh = (_Float16)w;
                half2v w2 = {wh, wh};
#pragma unroll
                for (int i = 0; i < 4; ++i) {
                    half2v bb = (half2v){k[t][2 * i], k[t][2 * i + 1]};
                    acc2[i] += w2 * bb;
                }
            }
            __builtin_amdgcn_s_setprio(0);
#pragma unroll
            for (int t = 0; t < 8; ++t) k[t] = nx[t];
        }
    }

    float inv = (deg > 0) ? 1.f / den : 0.f;
    ushort8 o;
#pragma unroll
    for (int i = 0; i < 4; ++i) {
        o[2 * i]     = f2h((float)acc2[i][0] * inv);
        o[2 * i + 1] = f2h((float)acc2[i][1] * inv);
    }
    *(ushort8*)(aggb + base) = o;   // cached: read 4x by gemm_wo
}

// ---------------------------------------------------------------------------
extern "C" void kernel_launch(void* const* d_in, const int* in_sizes, int n_in,
                              void* d_out, int out_size, void* d_ws, size_t ws_size,
                              hipStream_t stream)
{
    const float* h  = (const float*)d_in[0];
    const float* Wq = (const float*)d_in[1];
    const float* bq = (const float*)d_in[2];
    const float* Wk = (const float*)d_in[3];
    const float* bk = (const float*)d_in[4];
    const float* Wo = (const float*)d_in[5];
    const float* bo = (const float*)d_in[6];
    const int* rows = (const int*)d_in[7];
    const int* cols = (const int*)d_in[8];
    float* out = (float*)d_out;

    const int HID = 512;
    const int nN  = in_sizes[0] / HID;              // 25000
    const int E   = in_sizes[7];                    // 400000
    const int nPad = (nN + 127) & ~127;             // 25088
    const int nb = (nN + SCAN_CHUNK - 1) / SCAN_CHUNK;  // 13
    const int nbH = nPad * (HID / 8) / 256;         // conv_h blocks: 6272
    const int nbE4 = (E + 1023) / 1024;             // hist blocks: 391
    const int nScat8 = (((E + 255) / 256 + 7) & ~7);  // scatter blocks: 1568
    const int nMt = nPad / 128;                     // 196 M-tiles
    const int nGrp = (nMt + 7) / 8;                 // 25 XCD groups
    const int nGemmQK = nGrp * 64;                  // 1600 gemm blocks

    // workspace layout (all 16B-aligned), fp16 throughout (~81 MB)
    char* w = (char*)d_ws;
    u16* Kb  = (u16*)w;  w += (size_t)nPad * HID * 2;  // 25.7 MB
    u16* hh  = (u16*)w;  w += (size_t)nPad * HID * 2;  // 25.7 MB (reused as agg)
    u16* Qh  = (u16*)w;  w += (size_t)nPad * HID * 2;  // 25.7 MB
    u16* Wqt = (u16*)w;  w += 512 * 512 * 2;
    u16* Wkt = (u16*)w;  w += 512 * 512 * 2;
    u16* Wot = (u16*)w;  w += 512 * 512 * 2;
    float* bqp = (float*)w;  w += 512 * 4;
    float* bkp = (float*)w;  w += 512 * 4;
    int* rowptr = (int*)w;   w += (size_t)(nN + 1) * 4;
    int* cursor = (int*)w;   w += (size_t)nN * 4;
    int* deg    = (int*)w;   w += (size_t)nN * 4;
    int* bsum   = (int*)w;   w += 64 * 4;
    int* colc   = (int*)w;   /* E*4 */

    (void)hipMemsetAsync(deg, 0, (size_t)nN * sizeof(int), stream);

    // fused conv_h + hist + conv_w
    prep<<<nbH + nbE4 + 192, 256, 0, stream>>>(
        h, hh, nN, rows, deg, E, Wq, Wk, Wo, bq, bk,
        Wqt, Wkt, Wot, bqp, bkp, nbH, nbE4);

    // CSR scan in one dispatch (blocks self-compute their chunk prefix)
    scan_all<<<nb, 256, 0, stream>>>(deg, rowptr, cursor, nN, nb);

    // CSR scatter (first nScat8 blocks, overlaps GEMM ramp) + Q/K GEMMs
    gemm_qk<<<nScat8 + nGemmQK, 256, 0, stream>>>(
        hh, Wqt, Wkt, bqp, bkp, Qh, Kb, nPad,
        rows, cols, cursor, colc, E, nScat8);

    // fused SDDMM + softmax + aggregate -> fp16 agg (overwrites hh)
    node_agg<<<(nN + 3) / 4, 256, 0, stream>>>(Qh, Kb, rowptr, colc, hh, nN);

    // output projection, XCD-grouped (4 sharers per A-tile), NT f32 store
    gemm_wo<<<nGrp * 32, 256, 0, stream>>>(hh, Wot, bo, out, nN, nPad);
}

// Round 18
// 222.927 us; speedup vs baseline: 1.0224x; 1.0224x over previous
//
#include <hip/hip_runtime.h>
#include <math.h>

typedef unsigned short u16;
typedef unsigned int u32;
typedef __attribute__((ext_vector_type(8))) _Float16 half8;   // fp16x8
typedef __attribute__((ext_vector_type(2))) _Float16 half2v;  // fp16x2
typedef __attribute__((ext_vector_type(8))) u16 ushort8;
typedef __attribute__((ext_vector_type(4))) float f32x4;
typedef __attribute__((ext_vector_type(4))) int int4v;

__device__ __forceinline__ u16 f2h(float f) {
    union { u16 u; _Float16 h; } c; c.h = (_Float16)f; return c.u;
}

#if __has_builtin(__builtin_amdgcn_fdot2)
#define FDOT2(a, b, c) __builtin_amdgcn_fdot2((a), (b), (c), false)
#else
#define FDOT2(a, b, c) fmaf((float)(a)[0], (float)(b)[0], \
                        fmaf((float)(a)[1], (float)(b)[1], (c)))
#endif

// async global(16B) -> LDS, per-lane source addr, wave-linear LDS dest
__device__ __forceinline__ void gload16(void* lds, const void* g) {
    __builtin_amdgcn_global_load_lds(
        (const __attribute__((address_space(1))) u32*)g,
        (__attribute__((address_space(3))) u32*)lds,
        16, 0, 0);
}

// ---------------------------------------------------------------------------
// GEMM body: C[M,512] = A[M,512](fp16) @ Bt[512,512](fp16,[n][k]) + bias.
// r12-proven structure (60 us, FETCH 19 MB): 2-phase double-buffer, 32 KB
// LDS, one __syncthreads per k-step, STAGE(next) before COMPUTE(current).
// [Counted-vmcnt deep pipelines rejected: r10/r11/r14 all regressed.
//  Scatter-first reorder rejected: r17 regressed.]
// LDS tile [128][32]u16, XOR slot-swizzle (verified r6: bank conflicts -> 0).
// OUTMODE: 0 = f32 store, 1 = fp16 store, 2 = f32 nontemporal store.
// ---------------------------------------------------------------------------
template <int OUTMODE>
__device__ __forceinline__ void gemm_body(
    const u16* A, const u16* Bt, const float* bias, void* Cout, int Mout,
    int m0, int n0, u16* As0, u16* As1, u16* Bs0, u16* Bs1)
{
    const int tid  = threadIdx.x;
    const int wave = tid >> 6;
    const int lane = tid & 63;
    const int wr = (wave >> 1) * 64;
    const int wc = (wave & 1) * 64;

    f32x4 acc[4][4];
#pragma unroll
    for (int i = 0; i < 4; ++i)
#pragma unroll
        for (int j = 0; j < 4; ++j) acc[i][j] = (f32x4){0.f, 0.f, 0.f, 0.f};

    const int srow  = lane >> 2;                              // 0..15
    const int scolG = ((lane & 3) ^ ((srow >> 1) & 3)) * 8;   // swizzled global col
    const size_t gOffA = (size_t)(m0 + wave * 32 + srow) * 512 + scolG;
    const size_t gOffB = (size_t)(n0 + wave * 32 + srow) * 512 + scolG;
    const int lOff = wave * 1024 + srow * 32 + (lane & 3) * 8;  // linear dest

    const int fR = ((lane & 15) >> 1) & 3;
    const int paOff = (wr + (lane & 15)) * 32 + ((lane >> 4) ^ fR) * 8;
    const int pbOff = (wc + (lane & 15)) * 32 + ((lane >> 4) ^ fR) * 8;

    auto STAGE = [&](u16* sa, u16* sb, int ko) {
        gload16(sa + lOff,       A  + gOffA + ko);
        gload16(sa + lOff + 512, A  + gOffA + ko + 16 * 512);
        gload16(sb + lOff,       Bt + gOffB + ko);
        gload16(sb + lOff + 512, Bt + gOffB + ko + 16 * 512);
    };
    auto COMPUTE = [&](const u16* sa, const u16* sb) {
        half8 af[4], bf[4];
#pragma unroll
        for (int i = 0; i < 4; ++i) af[i] = *(const half8*)(sa + paOff + i * 512);
#pragma unroll
        for (int j = 0; j < 4; ++j) bf[j] = *(const half8*)(sb + pbOff + j * 512);
#pragma unroll
        for (int i = 0; i < 4; ++i)
#pragma unroll
            for (int j = 0; j < 4; ++j)
                acc[i][j] = __builtin_amdgcn_mfma_f32_16x16x32_f16(
                    af[i], bf[j], acc[i][j], 0, 0, 0);
    };

    STAGE(As0, Bs0, 0);
    __syncthreads();
#pragma unroll
    for (int kt = 0; kt < 16; kt += 2) {
        STAGE(As1, Bs1, (kt + 1) * 32);
        COMPUTE(As0, Bs0);
        __syncthreads();
        if (kt + 2 < 16) STAGE(As0, Bs0, (kt + 2) * 32);
        COMPUTE(As1, Bs1);
        __syncthreads();
    }

    const int ccol  = n0 + wc + (lane & 15);
    const int crow0 = m0 + wr + (lane >> 4) * 4;
#pragma unroll
    for (int j = 0; j < 4; ++j) {
        const float b = bias[ccol + j * 16];
#pragma unroll
        for (int i = 0; i < 4; ++i) {
#pragma unroll
            for (int r = 0; r < 4; ++r) {
                int row = crow0 + i * 16 + r;
                if (row < Mout) {
                    float v = acc[i][j][r] + b;
                    size_t off = (size_t)row * 512 + ccol + j * 16;
                    if (OUTMODE == 0)      ((float*)Cout)[off] = v;
                    else if (OUTMODE == 1) ((u16*)Cout)[off] = f2h(v);
                    else __builtin_nontemporal_store(v, (float*)Cout + off);
                }
            }
        }
    }
}

// Q and K projections in ONE dispatch, XCD-grouped block mapping (r12,
// verified FETCH 70->19 MB): the 8 blocks sharing an A M-tile get bids
// bid = 64*(m/8) + 8*s + (m%8) => same bid%8 (same XCD under round-robin)
// and adjacent dispatch order -> A-tile read once from HBM, 7x from L2.
// Blocks with bid >= nGemm do the CSR scatter (independent; completes
// within this dispatch, before node_agg).
__global__ __launch_bounds__(256) void gemm_qk(
    const u16* __restrict__ hh, const u16* __restrict__ Wqt,
    const u16* __restrict__ Wkt, const float* __restrict__ bqp,
    const float* __restrict__ bkp, u16* __restrict__ Qh,
    u16* __restrict__ Kb, int nPad,
    const int* __restrict__ rows, const int* __restrict__ cols,
    int* __restrict__ cursor, int* __restrict__ colc, int E, int nGemm)
{
    __shared__ __align__(16) u16 As0[4096], As1[4096], Bs0[4096], Bs1[4096];
    const int bid = blockIdx.x;
    if (bid >= nGemm) {
        // ---- fused CSR scatter ----
        int i = (bid - nGemm) * 256 + threadIdx.x;
        if (i < E) {
            int pos = atomicAdd(&cursor[rows[i]], 1);
            colc[pos] = cols[i];
        }
        return;
    }
    const int m = (bid >> 6) * 8 + (bid & 7);
    const int s = (bid >> 3) & 7;
    if (m >= nPad / 128) return;
    const int z = s >> 2;        // 0: Q, 1: K
    const int n = s & 3;         // N-tile

    const u16* Bt = z ? Wkt : Wqt;
    const float* bias = z ? bkp : bqp;
    u16* out = z ? Kb : Qh;
    gemm_body<1>(hh, Bt, bias, out, nPad, m * 128, n * 128,
                 As0, As1, Bs0, Bs1);
}

// Wo projection, XCD-grouping with 4 sharers per A M-tile:
// bid = 32*(m/8) + 8*s + (m%8), s in 0..3. NT store (output never re-read).
__global__ __launch_bounds__(256) void gemm_wo(
    const u16* __restrict__ A, const u16* __restrict__ Wot,
    const float* __restrict__ bo, float* __restrict__ C, int Mout, int nPad)
{
    const int bid = blockIdx.x;
    const int m = (bid >> 5) * 8 + (bid & 7);
    const int s = (bid >> 3) & 3;
    if (m >= nPad / 128) return;

    __shared__ __align__(16) u16 As0[4096], As1[4096], Bs0[4096], Bs1[4096];
    gemm_body<2>(A, Wot, bo, C, Mout, m * 128, s * 128,
                 As0, As1, Bs0, Bs1);
}

// ---------------------------------------------------------------------------
// prep: fused conv_h (h f32 -> fp16, pad zeroed) + hist (4 edges/thread) +
// conv_w. Grid: [0,nbH) conv_h, [nbH,nbH+nbE4) hist, [nbH+nbE4,+192) conv_w.
// ---------------------------------------------------------------------------
__global__ __launch_bounds__(256) void prep(
    const float* __restrict__ h, u16* __restrict__ hh, int nN,
    const int* __restrict__ rows, int* __restrict__ deg, int E,
    const float* __restrict__ Wq, const float* __restrict__ Wk,
    const float* __restrict__ Wo, const float* __restrict__ bq,
    const float* __restrict__ bk,
    u16* __restrict__ Wqt, u16* __restrict__ Wkt, u16* __restrict__ Wot,
    float* __restrict__ bqp, float* __restrict__ bkp,
    int nbH, int nbE4)
{
    __shared__ float T[64][65];
    const int tid = threadIdx.x;
    const int b = blockIdx.x;

    if (b < nbH) {
        // ---- conv_h ----
        int t = b * 256 + tid;
        size_t e = (size_t)t * 8;
        int row = (int)(e >> 9);
        ushort8 o;
        if (row < nN) {
            f32x4 a = *(const f32x4*)(h + e);
            f32x4 bb = *(const f32x4*)(h + e + 4);
            float x[8] = {a.x, a.y, a.z, a.w, bb.x, bb.y, bb.z, bb.w};
#pragma unroll
            for (int i = 0; i < 8; ++i) o[i] = f2h(x[i]);
        } else {
            o = (ushort8){0,0,0,0,0,0,0,0};
        }
        *(ushort8*)(hh + e) = o;
        return;
    }
    if (b < nbH + nbE4) {
        // ---- hist: 4 edges per thread ----
        int i = ((b - nbH) * 256 + tid) * 4;
        if (i + 3 < E) {
            int4v r = *(const int4v*)(rows + i);
            atomicAdd(&deg[r.x], 1);
            atomicAdd(&deg[r.y], 1);
            atomicAdd(&deg[r.z], 1);
            atomicAdd(&deg[r.w], 1);
        } else {
            for (int t = i; t < E; ++t) atomicAdd(&deg[rows[t]], 1);
        }
        return;
    }
    // ---- conv_w ----  (192 blocks: z = rem>>6, by = (rem&63)>>3, bx = rem&7)
    int rem = b - nbH - nbE4;
    const int z = rem >> 6;
    const int X = (rem & 7) * 64;
    const int Y = ((rem >> 3) & 7) * 64;

    const int r4 = tid >> 4;
    const int c4 = (tid & 15) * 4;
    if (z < 2) {
        const float* W = z ? Wk : Wq;
#pragma unroll
        for (int rr = 0; rr < 64; rr += 16) {
            f32x4 v = *(const f32x4*)(W + (size_t)(X + rr + r4) * 512 + Y + c4);
            T[rr + r4][c4 + 0] = v.x; T[rr + r4][c4 + 1] = v.y;
            T[rr + r4][c4 + 2] = v.z; T[rr + r4][c4 + 3] = v.w;
        }
    } else {
#pragma unroll
        for (int rr = 0; rr < 64; rr += 16) {
            int p2 = (rr + r4) * 8 + (X >> 6);   // perm(X + rr + r4)
            f32x4 v = *(const f32x4*)(Wo + (size_t)p2 * 512 + Y + c4);
            T[rr + r4][c4 + 0] = v.x; T[rr + r4][c4 + 1] = v.y;
            T[rr + r4][c4 + 2] = v.z; T[rr + r4][c4 + 3] = v.w;
        }
    }
    __syncthreads();

    const int cc = tid >> 2;
    const int ks = (tid & 3) * 16;
    const int pc = Y + cc;
    const int ro = (z < 2) ? ((pc & 7) * 64 + (pc >> 3)) : pc;
    ushort8 h0, h1;
#pragma unroll
    for (int t = 0; t < 8; ++t) {
        h0[t] = f2h(T[ks + t][cc]);
        h1[t] = f2h(T[ks + 8 + t][cc]);
    }
    size_t o = (size_t)ro * 512 + X + ks;
    if (z == 0) {
        *(ushort8*)(Wqt + o) = h0; *(ushort8*)(Wqt + o + 8) = h1;
    } else if (z == 1) {
        *(ushort8*)(Wkt + o) = h0; *(ushort8*)(Wkt + o + 8) = h1;
    } else {
        *(ushort8*)(Wot + o) = h0; *(ushort8*)(Wot + o + 8) = h1;
        if (rem == 128) {   // z==2, bx==0, by==0
            for (int bi = tid; bi < 512; bi += 256) {
                int pp = (bi & 63) * 8 + (bi >> 6);
                bqp[bi] = bq[pp];
                bkp[bi] = bk[pp];
            }
        }
    }
}

// ---------------------------------------------------------------------------
// Single-dispatch CSR scan: block b redundantly sums deg over chunks < b
// (max ~100 KB of reads at nb=13 -- trivial), then scans its own chunk.
// ---------------------------------------------------------------------------
#define SCAN_CHUNK 2048

__global__ __launch_bounds__(256) void scan_all(
    const int* __restrict__ deg, int* __restrict__ rowptr,
    int* __restrict__ cursor, int n, int nb)
{
    const int t = threadIdx.x;
    const int b = blockIdx.x;
    const int lane = t & 63, wv = t >> 6;
    __shared__ int ws[4], wsum[4];

    // prefix over preceding chunks
    int pre = 0;
    for (int i = t; i < b * SCAN_CHUNK; i += 256) pre += deg[i];
#pragma unroll
    for (int off = 1; off < 64; off <<= 1) pre += __shfl_xor(pre, off, 64);
    if (lane == 0) ws[wv] = pre;
    __syncthreads();
    const int boff = ws[0] + ws[1] + ws[2] + ws[3];

    // scan own chunk (8 elems/thread)
    int base = b * SCAN_CHUNK + t * 8;
    int v[8];
    int s = 0;
#pragma unroll
    for (int i = 0; i < 8; ++i) {
        int g = base + i;
        v[i] = (g < n) ? deg[g] : 0;
        s += v[i];
    }
    int inc = s;
#pragma unroll
    for (int off = 1; off < 64; off <<= 1) {
        int x = __shfl_up(inc, off, 64);
        if (lane >= off) inc += x;
    }
    if (lane == 63) wsum[wv] = inc;
    __syncthreads();
    int excl = boff + inc - s;
    for (int i = 0; i < wv; ++i) excl += wsum[i];
#pragma unroll
    for (int i = 0; i < 8; ++i) {
        int g = base + i;
        if (g < n) { rowptr[g] = excl; cursor[g] = excl; }
        excl += v[i];
    }
    if (b == nb - 1 && t == 0)
        rowptr[n] = boff + wsum[0] + wsum[1] + wsum[2] + wsum[3];
}

// ---------------------------------------------------------------------------
// Fused SDDMM + online segment softmax + SpMM. Head-major layout:
// lane l -> head l>>3, dims (l&7)*8..+7. One wave per node, 4 nodes/block.
// 8-edge unroll + depth-8 prefetch (8 KB in flight/wave). Packed fp16 math.
// setprio(1) around compute (T5, independent barrier-free waves). agg store
// CACHED (read 4x by gemm_wo's same-XCD sharers).
// v == k (source bug): K row loaded for the dot is reused for aggregation.
// ---------------------------------------------------------------------------
__global__ __launch_bounds__(256) void node_agg(
    const u16* __restrict__ Qh, const u16* __restrict__ Kb,
    const int* __restrict__ rowptr, const int* __restrict__ colc,
    u16* __restrict__ aggb, int nN)
{
    int node = blockIdx.x * 4 + (threadIdx.x >> 6);
    int lane = threadIdx.x & 63;
    if (node >= nN) return;
    size_t base = (size_t)node * 512 + lane * 8;

    half8 qv = __builtin_nontemporal_load((const half8*)(Qh + base));
    half2v q2[4];
#pragma unroll
    for (int i = 0; i < 4; ++i) q2[i] = (half2v){qv[2 * i], qv[2 * i + 1]};

    int start = rowptr[node];
    int deg   = rowptr[node + 1] - start;
    const int* cp = colc + start;
    const size_t loff = (size_t)lane * 8;

    float m = -__builtin_inff();
    float den = 0.f;
    half2v acc2[4];
#pragma unroll
    for (int i = 0; i < 4; ++i) acc2[i] = (half2v){(_Float16)0.f, (_Float16)0.f};

    if (deg > 0) {
        const int dl = deg - 1;
        half8 k[8];
#pragma unroll
        for (int t = 0; t < 8; ++t) {
            int it = t < dl ? t : dl;
            k[t] = *(const half8*)(Kb + (size_t)cp[it] * 512 + loff);
        }
        for (int j = 0; j < deg; j += 8) {
            half8 nx[8];
#pragma unroll
            for (int t = 0; t < 8; ++t) {
                int it = j + 8 + t < dl ? j + 8 + t : dl;
                nx[t] = *(const half8*)(Kb + (size_t)cp[it] * 512 + loff);
            }

            __builtin_amdgcn_s_setprio(1);
            float p[8];
#pragma unroll
            for (int t = 0; t < 8; ++t) {
                float s = 0.f;
#pragma unroll
                for (int i = 0; i < 4; ++i) {
                    half2v bb = (half2v){k[t][2 * i], k[t][2 * i + 1]};
                    s = FDOT2(q2[i], bb, s);
                }
                p[t] = s;
            }
#pragma unroll
            for (int off = 1; off < 8; off <<= 1) {
#pragma unroll
                for (int t = 0; t < 8; ++t) p[t] += __shfl_xor(p[t], off, 64);
            }

            // defer-max (THR=4, fp16-acc-safe): one check per 8-edge group
            float pm = p[0];
#pragma unroll
            for (int t = 1; t < 8; ++t) pm = fmaxf(pm, p[t]);
            if (__any(pm > m + 4.f)) {
                float mn = fmaxf(m, pm);
                float sc = __expf(m - mn);   // first group: exp(-inf)=0
                den *= sc;
                _Float16 sch = (_Float16)sc;
                half2v sc2 = {sch, sch};
#pragma unroll
                for (int i = 0; i < 4; ++i) acc2[i] *= sc2;
                m = mn;
            }
#pragma unroll
            for (int t = 0; t < 8; ++t) {
                float w = (j + t < deg) ? __expf(p[t] - m) : 0.f;  // <= e^4
                den += w;
                _Float16 wh = (_Float16)w;
                half2v w2 = {wh, wh};
#pragma unroll
                for (int i = 0; i < 4; ++i) {
                    half2v bb = (half2v){k[t][2 * i], k[t][2 * i + 1]};
                    acc2[i] += w2 * bb;
                }
            }
            __builtin_amdgcn_s_setprio(0);
#pragma unroll
            for (int t = 0; t < 8; ++t) k[t] = nx[t];
        }
    }

    float inv = (deg > 0) ? 1.f / den : 0.f;
    ushort8 o;
#pragma unroll
    for (int i = 0; i < 4; ++i) {
        o[2 * i]     = f2h((float)acc2[i][0] * inv);
        o[2 * i + 1] = f2h((float)acc2[i][1] * inv);
    }
    *(ushort8*)(aggb + base) = o;   // cached: read 4x by gemm_wo
}

// ---------------------------------------------------------------------------
extern "C" void kernel_launch(void* const* d_in, const int* in_sizes, int n_in,
                              void* d_out, int out_size, void* d_ws, size_t ws_size,
                              hipStream_t stream)
{
    const float* h  = (const float*)d_in[0];
    const float* Wq = (const float*)d_in[1];
    const float* bq = (const float*)d_in[2];
    const float* Wk = (const float*)d_in[3];
    const float* bk = (const float*)d_in[4];
    const float* Wo = (const float*)d_in[5];
    const float* bo = (const float*)d_in[6];
    const int* rows = (const int*)d_in[7];
    const int* cols = (const int*)d_in[8];
    float* out = (float*)d_out;

    const int HID = 512;
    const int nN  = in_sizes[0] / HID;              // 25000
    const int E   = in_sizes[7];                    // 400000
    const int nPad = (nN + 127) & ~127;             // 25088
    const int nb = (nN + SCAN_CHUNK - 1) / SCAN_CHUNK;  // 13
    const int nbH = nPad * (HID / 8) / 256;         // conv_h blocks: 6272
    const int nbE = (E + 255) / 256;                // scatter blocks: 1563
    const int nbE4 = (E + 1023) / 1024;             // hist blocks: 391
    const int nMt = nPad / 128;                     // 196 M-tiles
    const int nGrp = (nMt + 7) / 8;                 // 25 XCD groups
    const int nGemmQK = nGrp * 64;                  // 1600 gemm blocks

    // workspace layout (all 16B-aligned), fp16 throughout (~81 MB)
    char* w = (char*)d_ws;
    u16* Kb  = (u16*)w;  w += (size_t)nPad * HID * 2;  // 25.7 MB
    u16* hh  = (u16*)w;  w += (size_t)nPad * HID * 2;  // 25.7 MB (reused as agg)
    u16* Qh  = (u16*)w;  w += (size_t)nPad * HID * 2;  // 25.7 MB
    u16* Wqt = (u16*)w;  w += 512 * 512 * 2;
    u16* Wkt = (u16*)w;  w += 512 * 512 * 2;
    u16* Wot = (u16*)w;  w += 512 * 512 * 2;
    float* bqp = (float*)w;  w += 512 * 4;
    float* bkp = (float*)w;  w += 512 * 4;
    int* rowptr = (int*)w;   w += (size_t)(nN + 1) * 4;
    int* cursor = (int*)w;   w += (size_t)nN * 4;
    int* deg    = (int*)w;   w += (size_t)nN * 4;
    int* bsum   = (int*)w;   w += 64 * 4;
    int* colc   = (int*)w;   /* E*4 */

    (void)hipMemsetAsync(deg, 0, (size_t)nN * sizeof(int), stream);

    // fused conv_h + hist + conv_w
    prep<<<nbH + nbE4 + 192, 256, 0, stream>>>(
        h, hh, nN, rows, deg, E, Wq, Wk, Wo, bq, bk,
        Wqt, Wkt, Wot, bqp, bkp, nbH, nbE4);

    // CSR scan in one dispatch (blocks self-compute their chunk prefix)
    scan_all<<<nb, 256, 0, stream>>>(deg, rowptr, cursor, nN, nb);

    // Q + K projections (2-phase, XCD-grouped) + fused CSR scatter tail
    gemm_qk<<<nGemmQK + nbE, 256, 0, stream>>>(
        hh, Wqt, Wkt, bqp, bkp, Qh, Kb, nPad,
        rows, cols, cursor, colc, E, nGemmQK);

    // fused SDDMM + softmax + aggregate -> fp16 agg (overwrites hh)
    node_agg<<<(nN + 3) / 4, 256, 0, stream>>>(Qh, Kb, rowptr, colc, hh, nN);

    // output projection, XCD-grouped (4 sharers per A-tile), NT f32 store
    gemm_wo<<<nGrp * 32, 256, 0, stream>>>(hh, Wot, bo, out, nN, nPad);
}